// Round 16
// baseline (43.264 us; speedup 1.0000x reference)
//
#include <hip/hip_runtime.h>

// CARAFE naive upsample: N=2, C=256, H=100, W=100, K=5, G=1, S=2.
// out[n,c,2h+a,2w+b] = sum_{dy,dx} mask[n,dy*5+dx,2h+a,2w+b] * feat[n,c,h+dy-2,w+dx-2]
//
// Journal: R8 = 38.1 anchor; R13 = 37.1 best. R11: occupancy flat. R12: LDS
// masks wall. R13/R14: MLP pinning flat/regressed. R15: VMEM count 82->49
// flat. Shared unexplained term: every block pays cold L2/L3 latency on all
// 50 mask loads + barrier-serialized staging.
// R16: chunk-PAIR loop per block, double-buffered LDS:
//   stage A -> barrier -> issue B's staging loads (T14 issue-early/
//   write-late, sched_barrier pinned) -> compute+store A (cold masks) ->
//   write B -> barrier -> compute+store B (mask addresses IDENTICAL to A's
//   -> L1-hot, ~30cyc; staging latency hidden under A's compute).
//   1280 blocks = 5/CU exact, 20 waves/CU resident (> R8's ~10).

typedef float v2f __attribute__((ext_vector_type(2)));

#define N_ 2
#define C_ 256
#define H_ 100
#define W_ 100
#define CC 8
#define HW_ (H_ * W_)
#define OW_ (W_ * 2)
#define OHW_ (HW_ * 4)
#define NCPAIR 16                 // chunk pairs
#define TW 25
#define TH 10
#define HX 29                     // halo cols (TW+4)
#define NROW 28                   // 14 halo rows x 2 channel-quads
#define RSTR 29                   // float4 row stride: >= HX and odd
#define TILES_X (W_ / TW)         // 4
#define TILES_Y (H_ / TH)         // 10
#define TILES (TILES_X * TILES_Y) // 40

__global__ __launch_bounds__(256) void carafe_kernel(
    const float* __restrict__ feat,
    const float* __restrict__ mask,
    float* __restrict__ out) {

    __shared__ float4 lds4[2][NROW * RSTR];   // 2 x 12,992 B

    const int cpair = blockIdx.x;
    const int tile  = blockIdx.y;
    const int n     = blockIdx.z;
    const int tx = tile % TILES_X;
    const int ty = tile / TILES_X;
    const int x0 = tx * TW;
    const int y0 = ty * TH;
    const int t = threadIdx.x;
    const int lane = t & 31;
    const int g = t >> 5;

    const int hl = t / TW;                 // valid when t < 250
    const int wl = t % TW;
    const int oh0 = 2 * (y0 + hl);
    const int ow0 = 2 * (x0 + wl);
    const float* mbase = mask + n * (25 * OHW_) + oh0 * OW_ + ow0;
    const bool comp = (t < TH * TW);

    const int xx = x0 - 2 + lane;
    const bool xok = (lane < HX) & ((unsigned)xx < (unsigned)W_);

#define LOADC(chunk, SR)                                                      \
    do {                                                                      \
        const float* fb_ = feat + (n * C_ + (chunk) * CC) * HW_;              \
        _Pragma("unroll")                                                     \
        for (int r = 0; r < 4; ++r) {                                         \
            const int p_ = g * 4 + r;                                         \
            const int yy_ = y0 - 2 + (p_ >> 1);                               \
            float4 v_ = make_float4(0.f, 0.f, 0.f, 0.f);                      \
            if (xok & ((unsigned)yy_ < (unsigned)H_) & (p_ < NROW)) {         \
                const int o_ = ((p_ & 1) * 4) * HW_ + yy_ * W_ + xx;          \
                v_.x = fb_[o_];                                               \
                v_.y = fb_[o_ + HW_];                                         \
                v_.z = fb_[o_ + 2 * HW_];                                     \
                v_.w = fb_[o_ + 3 * HW_];                                     \
            }                                                                 \
            SR[r] = v_;                                                       \
        }                                                                     \
    } while (0)

#define WRITEB(buf, SR)                                                       \
    do {                                                                      \
        _Pragma("unroll")                                                     \
        for (int r = 0; r < 4; ++r) {                                         \
            const int p_ = g * 4 + r;                                         \
            if ((p_ < NROW) & (lane < HX))                                    \
                (buf)[p_ * RSTR + lane] = SR[r];                              \
        }                                                                     \
    } while (0)

#define COMPUTE(buf, chunk)                                                   \
    do {                                                                      \
        if (comp) {                                                           \
            v2f a0_[CC], a1_[CC];                                             \
            _Pragma("unroll")                                                 \
            for (int c = 0; c < CC; ++c) {                                    \
                a0_[c] = (v2f){0.f, 0.f};                                     \
                a1_[c] = (v2f){0.f, 0.f};                                     \
            }                                                                 \
            _Pragma("unroll 1")                                               \
            for (int dy = 0; dy < 5; ++dy) {                                  \
                const int ry_ = (hl + dy) * 2;                                \
                const float* mr_ = mbase + (dy * 5) * OHW_;                   \
                _Pragma("unroll")                                             \
                for (int dx = 0; dx < 5; ++dx) {                              \
                    const v2f m0_ = *reinterpret_cast<const v2f*>(mr_ + dx * OHW_);       \
                    const v2f m1_ = *reinterpret_cast<const v2f*>(mr_ + dx * OHW_ + OW_); \
                    const float4 lo_ = (buf)[ry_ * RSTR + wl + dx];           \
                    const float4 hi_ = (buf)[(ry_ + 1) * RSTR + wl + dx];     \
                    const float f_[8] = {lo_.x, lo_.y, lo_.z, lo_.w,          \
                                         hi_.x, hi_.y, hi_.z, hi_.w};         \
                    _Pragma("unroll")                                         \
                    for (int c = 0; c < CC; ++c) {                            \
                        const v2f fv_ = {f_[c], f_[c]};                       \
                        a0_[c] = __builtin_elementwise_fma(fv_, m0_, a0_[c]); \
                        a1_[c] = __builtin_elementwise_fma(fv_, m1_, a1_[c]); \
                    }                                                         \
                }                                                             \
            }                                                                 \
            float* ob_ = out + (n * C_ + (chunk) * CC) * OHW_ + oh0 * OW_ + ow0; \
            _Pragma("unroll")                                                 \
            for (int c = 0; c < CC; ++c) {                                    \
                *reinterpret_cast<v2f*>(ob_ + c * OHW_) = a0_[c];             \
                *reinterpret_cast<v2f*>(ob_ + c * OHW_ + OW_) = a1_[c];       \
            }                                                                 \
        }                                                                     \
    } while (0)

    const int cA = cpair * 2;
    const int cB = cpair * 2 + 1;

    float4 srA[4], srB[4];

    LOADC(cA, srA);
    WRITEB(lds4[0], srA);
    __syncthreads();

    LOADC(cB, srB);                        // issue B's staging loads early
    __builtin_amdgcn_sched_barrier(0);     // don't sink them into compute
    COMPUTE(lds4[0], cA);                  // cold masks, staging B in flight
    __builtin_amdgcn_sched_barrier(0);     // don't hoist the ds_writes up
    WRITEB(lds4[1], srB);
    __syncthreads();

    COMPUTE(lds4[1], cB);                  // masks L1-hot (same addresses)

#undef LOADC
#undef WRITEB
#undef COMPUTE
}

extern "C" void kernel_launch(void* const* d_in, const int* in_sizes, int n_in,
                              void* d_out, int out_size, void* d_ws, size_t ws_size,
                              hipStream_t stream) {
    const float* feat = (const float*)d_in[0];
    const float* mask = (const float*)d_in[1];
    float* out = (float*)d_out;

    dim3 grid(NCPAIR, TILES, N_);   // 16 x 40 x 2 = 1280 blocks
    carafe_kernel<<<grid, 256, 0, stream>>>(feat, mask, out);
}

// Round 17
// 39.963 us; speedup vs baseline: 1.0826x; 1.0826x over previous
//
#include <hip/hip_runtime.h>

// CARAFE naive upsample: N=2, C=256, H=100, W=100, K=5, G=1, S=2.
// out[n,c,2h+a,2w+b] = sum_{dy,dx} mask[n,dy*5+dx,2h+a,2w+b] * feat[n,c,h+dy-2,w+dx-2]
//
// Journal: R8=38.1 anchor; R13=37.1 best (sched_barrier pipeline, pin failed:
// VGPR 60). R11: occupancy 56% flat -> TLP alone not the fix. R14: asm vmcnt
// pipeline poisoned by nt-store write amplification (80->105MB) + rigid A/B/C
// register reuse. R15: VMEM count 82->49 flat. R16: chunk-pair dbuf 43.3 (L3
// hit-rate loss). Latency-hiding product needed ~23 (waves x loads-in-flight);
// never cleanly achieved. R17 = the clean experiment:
//   R13 structure + ALL 50 mask loads issued up front as asm volatile
//   global_load_dwordx2 (saddr + 32-bit voffset, offset:800 for a=1 row),
//   monotone drain vmcnt(40/30/20/10/0) + sched_barrier(0) (rule #18),
//   dedicated registers per load (no reuse hazards), NORMAL stores.
//   In-flight product = 3 waves x 50 = 150 >> 23. VGPR >=130 proves the pin.

typedef float v2f __attribute__((ext_vector_type(2)));

#define N_ 2
#define C_ 256
#define H_ 100
#define W_ 100
#define CC 8
#define HW_ (H_ * W_)
#define OW_ (W_ * 2)
#define OHW_ (HW_ * 4)
#define NCHUNK (C_ / CC)          // 32
#define TW 25
#define TH 10
#define HX 29                     // halo cols (TW+4)
#define NROW 28                   // 14 halo rows x 2 channel-quads
#define RSTR 29                   // float4 row stride: >= HX and odd
#define TILES_X (W_ / TW)         // 4
#define TILES_Y (H_ / TH)         // 10
#define TILES (TILES_X * TILES_Y) // 40

__global__ __launch_bounds__(256) void carafe_kernel(
    const float* __restrict__ feat,
    const float* __restrict__ mask,
    float* __restrict__ out) {

    __shared__ float4 lds4[NROW * RSTR];   // 12,992 B

    const int cchunk = blockIdx.x;
    const int tile   = blockIdx.y;
    const int n      = blockIdx.z;
    const int tx = tile % TILES_X;
    const int ty = tile / TILES_X;
    const int x0 = tx * TW;
    const int y0 = ty * TH;
    const int t = threadIdx.x;
    const int lane = t & 31;
    const int g = t >> 5;

    // ---- stage features (identical to R8/R13) ----
    {
        const float* fb = feat + (n * C_ + cchunk * CC) * HW_;
        const int xx = x0 - 2 + lane;
        const bool xok = (lane < HX) & ((unsigned)xx < (unsigned)W_);
#pragma unroll
        for (int r = 0; r < 4; ++r) {
            const int p = g * 4 + r;
            const int y = p >> 1;
            const int cq = p & 1;
            const int yy = y0 - 2 + y;
            float v0 = 0.f, v1 = 0.f, v2 = 0.f, v3 = 0.f;
            if (xok & ((unsigned)yy < (unsigned)H_) & (p < NROW)) {
                const int o = (cq * 4) * HW_ + yy * W_ + xx;
                v0 = fb[o];
                v1 = fb[o + HW_];
                v2 = fb[o + 2 * HW_];
                v3 = fb[o + 3 * HW_];
            }
            if ((p < NROW) & (lane < HX))
                lds4[p * RSTR + lane] = make_float4(v0, v1, v2, v3);
        }
    }
    __syncthreads();   // compiler drains vmcnt before ds_write -> 0 outstanding here

    if (t >= TH * TW) return;              // 250 compute threads
    const int hl = t / TW;
    const int wl = t % TW;

    v2f a0[CC], a1[CC];
#pragma unroll
    for (int c = 0; c < CC; ++c) { a0[c] = (v2f){0.f, 0.f}; a1[c] = (v2f){0.f, 0.f}; }

    const int oh0 = 2 * (y0 + hl);
    const int ow0 = 2 * (x0 + wl);
    const float* mbase = mask + n * (25 * OHW_);                // SGPR pair
    const unsigned thr_off = (unsigned)(oh0 * OW_ + ow0) * 4u;  // per-thread bytes

    // 25 dedicated register pairs per a-row: no reuse, no mid-pipe hazards.
    v2f mm0[25], mm1[25];

#define ISSUE(dyv)                                                                  \
    do {                                                                            \
        const unsigned vo0 = thr_off + (unsigned)((((dyv) * 5 + 0) * OHW_) * 4);    \
        const unsigned vo1 = thr_off + (unsigned)((((dyv) * 5 + 1) * OHW_) * 4);    \
        const unsigned vo2 = thr_off + (unsigned)((((dyv) * 5 + 2) * OHW_) * 4);    \
        const unsigned vo3 = thr_off + (unsigned)((((dyv) * 5 + 3) * OHW_) * 4);    \
        const unsigned vo4 = thr_off + (unsigned)((((dyv) * 5 + 4) * OHW_) * 4);    \
        asm volatile("global_load_dwordx2 %0, %1, %2 offset:0"   : "=v"(mm0[(dyv)*5+0]) : "v"(vo0), "s"(mbase)); \
        asm volatile("global_load_dwordx2 %0, %1, %2 offset:800" : "=v"(mm1[(dyv)*5+0]) : "v"(vo0), "s"(mbase)); \
        asm volatile("global_load_dwordx2 %0, %1, %2 offset:0"   : "=v"(mm0[(dyv)*5+1]) : "v"(vo1), "s"(mbase)); \
        asm volatile("global_load_dwordx2 %0, %1, %2 offset:800" : "=v"(mm1[(dyv)*5+1]) : "v"(vo1), "s"(mbase)); \
        asm volatile("global_load_dwordx2 %0, %1, %2 offset:0"   : "=v"(mm0[(dyv)*5+2]) : "v"(vo2), "s"(mbase)); \
        asm volatile("global_load_dwordx2 %0, %1, %2 offset:800" : "=v"(mm1[(dyv)*5+2]) : "v"(vo2), "s"(mbase)); \
        asm volatile("global_load_dwordx2 %0, %1, %2 offset:0"   : "=v"(mm0[(dyv)*5+3]) : "v"(vo3), "s"(mbase)); \
        asm volatile("global_load_dwordx2 %0, %1, %2 offset:800" : "=v"(mm1[(dyv)*5+3]) : "v"(vo3), "s"(mbase)); \
        asm volatile("global_load_dwordx2 %0, %1, %2 offset:0"   : "=v"(mm0[(dyv)*5+4]) : "v"(vo4), "s"(mbase)); \
        asm volatile("global_load_dwordx2 %0, %1, %2 offset:800" : "=v"(mm1[(dyv)*5+4]) : "v"(vo4), "s"(mbase)); \
    } while (0)

#define WAITV(nv)                                                                   \
    do {                                                                            \
        asm volatile("s_waitcnt vmcnt(" #nv ")");                                   \
        __builtin_amdgcn_sched_barrier(0);                                          \
    } while (0)

#define STAGE(dyv)                                                                  \
    do {                                                                            \
        const int ry_ = (hl + (dyv)) * 2;                                           \
        float4 lo_[5], hi_[5];                                                      \
        _Pragma("unroll")                                                           \
        for (int dx = 0; dx < 5; ++dx) {                                            \
            lo_[dx] = lds4[ry_ * RSTR + wl + dx];                                   \
            hi_[dx] = lds4[(ry_ + 1) * RSTR + wl + dx];                             \
        }                                                                           \
        _Pragma("unroll")                                                           \
        for (int dx = 0; dx < 5; ++dx) {                                            \
            const float f_[8] = {lo_[dx].x, lo_[dx].y, lo_[dx].z, lo_[dx].w,        \
                                 hi_[dx].x, hi_[dx].y, hi_[dx].z, hi_[dx].w};       \
            _Pragma("unroll")                                                       \
            for (int c = 0; c < CC; ++c) {                                          \
                const v2f fv_ = {f_[c], f_[c]};                                     \
                a0[c] = __builtin_elementwise_fma(fv_, mm0[(dyv) * 5 + dx], a0[c]); \
                a1[c] = __builtin_elementwise_fma(fv_, mm1[(dyv) * 5 + dx], a1[c]); \
            }                                                                       \
        }                                                                           \
    } while (0)

    // ---- issue everything, then monotone drain (never early-0) ----
    ISSUE(0); ISSUE(1); ISSUE(2); ISSUE(3); ISSUE(4);   // 50 outstanding
    WAITV(40); STAGE(0);
    WAITV(30); STAGE(1);
    WAITV(20); STAGE(2);
    WAITV(10); STAGE(3);
    WAITV(0);  STAGE(4);

#undef ISSUE
#undef WAITV
#undef STAGE

    float* ob = out + (n * C_ + cchunk * CC) * OHW_ + oh0 * OW_ + ow0;
#pragma unroll
    for (int c = 0; c < CC; ++c) {
        *reinterpret_cast<v2f*>(ob + c * OHW_) = a0[c];
        *reinterpret_cast<v2f*>(ob + c * OHW_ + OW_) = a1[c];
    }
}

extern "C" void kernel_launch(void* const* d_in, const int* in_sizes, int n_in,
                              void* d_out, int out_size, void* d_ws, size_t ws_size,
                              hipStream_t stream) {
    const float* feat = (const float*)d_in[0];
    const float* mask = (const float*)d_in[1];
    float* out = (float*)d_out;

    dim3 grid(NCHUNK, TILES, N_);   // 32 x 40 x 2 = 2560 blocks
    carafe_kernel<<<grid, 256, 0, stream>>>(feat, mask, out);
}

// Round 18
// 37.237 us; speedup vs baseline: 1.1618x; 1.0732x over previous
//
#include <hip/hip_runtime.h>

// CARAFE naive upsample: N=2, C=256, H=100, W=100, K=5, G=1, S=2.
// out[n,c,2h+a,2w+b] = sum_{dy,dx} mask[n,dy*5+dx,2h+a,2w+b] * feat[n,c,h+dy-2,w+dx-2]
//
// Journal: R8=38.1; R13=37.1 best. R11 (occ 56%), R14/R17 (asm-pinned MLP
// 30-50 deep) all flat => neither occupancy nor mask latency is binding.
// Cross-round fact: dur 37-40 us across every within-block reorganization.
// Per-CU budget: VMEM+LDS+VALU pipe times SUM to the runtime (no overlap).
// Dominant stream: 50 mask VMEM instrs/thread re-executed by all 32
// chunk-blocks over the same tile (32x redundant).
// R18: 2 chunks per block; masks loaded ONCE into 100 VGPRs and reused by
// both chunks (guaranteed, vs R16's reload-and-pray-L1). Double-buffered
// feature LDS; chunk B staging issued before chunk A compute (T14), written
// after. 1280 blocks = 5/CU exact. Halves the mask stream, doubles compute
// per staging phase.

typedef float v2f __attribute__((ext_vector_type(2)));

#define N_ 2
#define C_ 256
#define H_ 100
#define W_ 100
#define CC 8
#define HW_ (H_ * W_)
#define OW_ (W_ * 2)
#define OHW_ (HW_ * 4)
#define NCPAIR 16                 // chunk pairs
#define TW 25
#define TH 10
#define HX 29                     // halo cols (TW+4)
#define NROW 28                   // 14 halo rows x 2 channel-quads
#define RSTR 29                   // float4 row stride (odd, >= HX)
#define TILES_X (W_ / TW)         // 4
#define TILES_Y (H_ / TH)         // 10
#define TILES (TILES_X * TILES_Y) // 40

__global__ __launch_bounds__(256) void carafe_kernel(
    const float* __restrict__ feat,
    const float* __restrict__ mask,
    float* __restrict__ out) {

    __shared__ float4 lds4[2][NROW * RSTR];   // 2 x 12,992 B = 25,984 B

    const int cpair = blockIdx.x;
    const int tile  = blockIdx.y;
    const int n     = blockIdx.z;
    const int tx = tile % TILES_X;
    const int ty = tile / TILES_X;
    const int x0 = tx * TW;
    const int y0 = ty * TH;
    const int t = threadIdx.x;
    const int lane = t & 31;
    const int g = t >> 5;

    const bool comp = (t < TH * TW);          // 250 compute threads
    const int hl = min(t / TW, TH - 1);       // clamp dead lanes in-bounds
    const int wl = t % TW;
    const int oh0 = 2 * (y0 + hl);
    const int ow0 = 2 * (x0 + wl);
    const float* mbase = mask + n * (25 * OHW_) + oh0 * OW_ + ow0;

    const int xx = x0 - 2 + lane;
    const bool xok = (lane < HX) & ((unsigned)xx < (unsigned)W_);

#define LOADC(chunk, SR)                                                      \
    do {                                                                      \
        const float* fb_ = feat + (n * C_ + (chunk) * CC) * HW_;              \
        _Pragma("unroll")                                                     \
        for (int r = 0; r < 4; ++r) {                                         \
            const int p_ = g * 4 + r;                                         \
            const int yy_ = y0 - 2 + (p_ >> 1);                               \
            float4 v_ = make_float4(0.f, 0.f, 0.f, 0.f);                      \
            if (xok & ((unsigned)yy_ < (unsigned)H_) & (p_ < NROW)) {         \
                const int o_ = ((p_ & 1) * 4) * HW_ + yy_ * W_ + xx;          \
                v_.x = fb_[o_];                                               \
                v_.y = fb_[o_ + HW_];                                         \
                v_.z = fb_[o_ + 2 * HW_];                                     \
                v_.w = fb_[o_ + 3 * HW_];                                     \
            }                                                                 \
            SR[r] = v_;                                                       \
        }                                                                     \
    } while (0)

#define WRITEB(bi, SR)                                                        \
    do {                                                                      \
        _Pragma("unroll")                                                     \
        for (int r = 0; r < 4; ++r) {                                         \
            const int p_ = g * 4 + r;                                         \
            if ((p_ < NROW) & (lane < HX))                                    \
                lds4[bi][p_ * RSTR + lane] = SR[r];                           \
        }                                                                     \
    } while (0)

// masks come from registers m0[]/m1[] (static indices, fully unrolled)
#define COMPUTE(bi, chunk)                                                    \
    do {                                                                      \
        if (comp) {                                                           \
            v2f a0_[CC], a1_[CC];                                             \
            _Pragma("unroll")                                                 \
            for (int c = 0; c < CC; ++c) {                                    \
                a0_[c] = (v2f){0.f, 0.f};                                     \
                a1_[c] = (v2f){0.f, 0.f};                                     \
            }                                                                 \
            _Pragma("unroll")                                                 \
            for (int dy = 0; dy < 5; ++dy) {                                  \
                const int ry_ = (hl + dy) * 2;                                \
                _Pragma("unroll")                                             \
                for (int dx = 0; dx < 5; ++dx) {                              \
                    const float4 lo_ = lds4[bi][ry_ * RSTR + wl + dx];        \
                    const float4 hi_ = lds4[bi][(ry_ + 1) * RSTR + wl + dx];  \
                    const float f_[8] = {lo_.x, lo_.y, lo_.z, lo_.w,          \
                                         hi_.x, hi_.y, hi_.z, hi_.w};         \
                    _Pragma("unroll")                                         \
                    for (int c = 0; c < CC; ++c) {                            \
                        const v2f fv_ = {f_[c], f_[c]};                       \
                        a0_[c] = __builtin_elementwise_fma(fv_, m0[dy * 5 + dx], a0_[c]); \
                        a1_[c] = __builtin_elementwise_fma(fv_, m1[dy * 5 + dx], a1_[c]); \
                    }                                                         \
                }                                                             \
            }                                                                 \
            float* ob_ = out + (n * C_ + (chunk) * CC) * OHW_ + oh0 * OW_ + ow0; \
            _Pragma("unroll")                                                 \
            for (int c = 0; c < CC; ++c) {                                    \
                *reinterpret_cast<v2f*>(ob_ + c * OHW_) = a0_[c];             \
                *reinterpret_cast<v2f*>(ob_ + c * OHW_ + OW_) = a1_[c];       \
            }                                                                 \
        }                                                                     \
    } while (0)

    const int cA = cpair * 2;
    const int cB = cpair * 2 + 1;

    float4 srA[4], srB[4];

    // ---- stage chunk A + load ALL masks into registers (once) ----
    LOADC(cA, srA);
    WRITEB(0, srA);

    v2f m0[25], m1[25];
#pragma unroll
    for (int k = 0; k < 25; ++k) {
        const float* mr = mbase + k * OHW_;
        m0[k] = *reinterpret_cast<const v2f*>(mr);        // a=0
        m1[k] = *reinterpret_cast<const v2f*>(mr + OW_);  // a=1
    }
    __syncthreads();

    // ---- issue chunk B staging loads early (T14), then compute A ----
    LOADC(cB, srB);
    __builtin_amdgcn_sched_barrier(0);
    COMPUTE(0, cA);
    __builtin_amdgcn_sched_barrier(0);
    WRITEB(1, srB);
    __syncthreads();

    // ---- compute B from the SAME mask registers ----
    COMPUTE(1, cB);

#undef LOADC
#undef WRITEB
#undef COMPUTE
}

extern "C" void kernel_launch(void* const* d_in, const int* in_sizes, int n_in,
                              void* d_out, int out_size, void* d_ws, size_t ws_size,
                              hipStream_t stream) {
    const float* feat = (const float*)d_in[0];
    const float* mask = (const float*)d_in[1];
    float* out = (float*)d_out;

    dim3 grid(NCPAIR, TILES, N_);   // 16 x 40 x 2 = 1280 blocks
    carafe_kernel<<<grid, 256, 0, stream>>>(feat, mask, out);
}